// Round 9
// baseline (931.545 us; speedup 1.0000x reference)
//
#include <hip/hip_runtime.h>
#include <hip/hip_bf16.h>
#include <cstdint>
#include <cstddef>

// NaryTreeLSTM bottom-up:
//  - gemm_zx: preZ[node][4*256] = x @ [Wi|Wo|Wu|Wf]^T + bias for nodes 0..2046
//  - levels 15..11 (n>=2048): fused LDS-tiled MFMA kernel, one launch each
//  - levels 10..6: ONE 64-block kernel; U-weights LDS-stationary per d-tile,
//    hierarchical (8x8) grid barrier, 4 barriers total.
//  - levels 5..0: ONE single-workgroup kernel (1024 thr = 16 waves, one CU);
//    __syncthreads() between levels, weights from L2. Writes root h,c to out.
//    Register-budgeted: af preloaded per-phase only (32 VGPRs), lb(1024,1).
//
// Wpack[12][256][256] bf16: mats {Wi,Wo,Wu,Wf, Ui0,Uo0,Uu0,Uf0, Ui1,Uo1,Uu1,Uf1}
// biasv[4][256] fp32. h stored bf16, c fp32.
// f gates: f_l = sig(Wf x + bF + Uf0 h_l), f_r = sig(Wf x + bF + Uf1 h_r).

typedef __attribute__((ext_vector_type(8))) __bf16 bf16x8;
typedef __attribute__((ext_vector_type(4))) float floatx4;

#define TB 64   // tail grid: 16 d-tiles x 4 m-groups

__device__ __forceinline__ float sigf(float x) { return 1.0f / (1.0f + __expf(-x)); }

__device__ __forceinline__ void load_lds16(const void* g, void* l) {
    __builtin_amdgcn_global_load_lds(
        (const __attribute__((address_space(1))) unsigned int*)g,
        (__attribute__((address_space(3))) unsigned int*)l, 16, 0, 0);
}

__global__ void pack_weights(const float* __restrict__ Wi, const float* __restrict__ bi, const float* __restrict__ Ui,
                             const float* __restrict__ Wo, const float* __restrict__ bo, const float* __restrict__ Uo,
                             const float* __restrict__ Wu, const float* __restrict__ bu, const float* __restrict__ Uu,
                             const float* __restrict__ Wf, const float* __restrict__ bf, const float* __restrict__ Uf,
                             __hip_bfloat16* __restrict__ Wpack, float* __restrict__ biasv)
{
    int m = blockIdx.x;   // 0..11
    int d = blockIdx.y;   // 0..255
    int k = threadIdx.x;  // 0..255
    const float* tbl[12] = {Wi, Wo, Wu, Wf,
                            Ui, Uo, Uu, Uf,
                            Ui + 65536, Uo + 65536, Uu + 65536, Uf + 65536};
    Wpack[((size_t)m * 256 + d) * 256 + k] = __float2bfloat16(tbl[m][d * 256 + k]);
    if (m < 4 && k == 0) {
        const float* bt[4] = {bi, bo, bu, bf};
        biasv[m * 256 + d] = bt[m][d];
    }
}

__global__ void convert_f32_bf16(const float* __restrict__ in, __hip_bfloat16* __restrict__ out, int n4)
{
    int i = blockIdx.x * 256 + threadIdx.x;
    if (i >= n4) return;
    float4 v = ((const float4*)in)[i];
    __hip_bfloat16 tmp[4];
    tmp[0] = __float2bfloat16(v.x);
    tmp[1] = __float2bfloat16(v.y);
    tmp[2] = __float2bfloat16(v.z);
    tmp[3] = __float2bfloat16(v.w);
    *(ushort4*)(out + (size_t)i * 4) = *(const ushort4*)tmp;
}

// preZ[m][s*256+d] = sum_k embB[m][k]*Wpack[s*256+d][k] + biasv[s*256+d], m<M
__global__ __launch_bounds__(256) void gemm_zx(
    const __hip_bfloat16* __restrict__ embB,
    const __hip_bfloat16* __restrict__ Wpack,
    const float* __restrict__ biasv,
    float* __restrict__ preZ,
    int M)
{
    __shared__ __hip_bfloat16 sA[64 * 32];
    __shared__ __hip_bfloat16 sB[64 * 32];
    const int t = threadIdx.x;
    const int s = blockIdx.x >> 2;
    const int d0 = (blockIdx.x & 3) * 64;
    const int bm0 = blockIdx.y * 64;
    const int lane = t & 63, w = t >> 6, lrow = lane & 15, q = lane >> 4;

    floatx4 acc[4];
    #pragma unroll
    for (int mt = 0; mt < 4; ++mt) acc[mt] = (floatx4){0.f, 0.f, 0.f, 0.f};

    for (int kk = 0; kk < 8; ++kk) {
        const int k0 = kk * 32;
        {
            int r = t >> 2, kc = t & 3;
            load_lds16(embB + (size_t)(bm0 + r) * 256 + k0 + kc * 8, &sA[t * 8]);
            load_lds16(Wpack + (size_t)(s * 256 + d0 + r) * 256 + k0 + kc * 8, &sB[t * 8]);
        }
        __syncthreads();
        bf16x8 af[4];
        #pragma unroll
        for (int mt = 0; mt < 4; ++mt)
            af[mt] = *(const bf16x8*)&sA[(mt * 16 + lrow) * 32 + q * 8];
        bf16x8 bfr = *(const bf16x8*)&sB[(w * 16 + lrow) * 32 + q * 8];
        #pragma unroll
        for (int mt = 0; mt < 4; ++mt)
            acc[mt] = __builtin_amdgcn_mfma_f32_16x16x32_bf16(af[mt], bfr, acc[mt], 0, 0, 0);
        __syncthreads();
    }

    const int d = d0 + w * 16 + lrow;
    const float bv = biasv[s * 256 + d];
    #pragma unroll
    for (int mt = 0; mt < 4; ++mt)
        #pragma unroll
        for (int rr = 0; rr < 4; ++rr) {
            int m = bm0 + mt * 16 + q * 4 + rr;
            if (m < M) preZ[(size_t)m * 1024 + s * 256 + d] = acc[mt][rr] + bv;
        }
}

// ---- big levels: fused LDS-tiled kernel -----------------------------------
template<int NS, int NP>
__global__ __launch_bounds__(256) void fused_level(
    const __hip_bfloat16* __restrict__ embX,
    const __hip_bfloat16* __restrict__ hprev,
    const float* __restrict__ cprev,
    const __hip_bfloat16* __restrict__ Wpack,
    const float* __restrict__ biasv,
    __hip_bfloat16* __restrict__ hout,
    float* __restrict__ cout,
    int M)
{
    __shared__ __hip_bfloat16 sA[64 * 32];
    __shared__ __hip_bfloat16 sB[NS * 64 * 32];
    const int t = threadIdx.x;
    const int dchunk = blockIdx.x;
    const int bm0 = blockIdx.y * 64;
    const int lane = t & 63;
    const int w = t >> 6;
    const int lrow = lane & 15;
    const int q = lane >> 4;

    floatx4 accS[3][4];
    floatx4 accF[NP][4];
    #pragma unroll
    for (int s = 0; s < 3; ++s)
        #pragma unroll
        for (int mt = 0; mt < 4; ++mt) accS[s][mt] = (floatx4){0.f, 0.f, 0.f, 0.f};
    #pragma unroll
    for (int p = 0; p < NP; ++p)
        #pragma unroll
        for (int mt = 0; mt < 4; ++mt) accF[p][mt] = (floatx4){0.f, 0.f, 0.f, 0.f};

    #pragma unroll
    for (int p = 0; p < NP; ++p) {
        const __hip_bfloat16* Abase = (p == 0) ? embX : hprev;
        const int astride = (p == 0) ? 256 : 512;
        const int aoff = (p == 0) ? 0 : (p - 1) * 256;
        for (int kk = 0; kk < 8; ++kk) {
            const int k0 = kk * 32;
            {
                int r = t >> 2, kc = t & 3;
                load_lds16(Abase + (size_t)(bm0 + r) * astride + aoff + k0 + kc * 8,
                           &sA[t * 8]);
            }
            #pragma unroll
            for (int rep = 0; rep < NS; ++rep) {
                int cid = rep * 256 + t;
                int row = cid >> 2, kc = cid & 3;
                int s = row >> 6, r = row & 63;
                load_lds16(Wpack + (size_t)((p * 4 + s) * 256 + dchunk * 64 + r) * 256 + k0 + kc * 8,
                           &sB[cid * 8]);
            }
            __syncthreads();

            bf16x8 af[4];
            #pragma unroll
            for (int mt = 0; mt < 4; ++mt)
                af[mt] = *(const bf16x8*)&sA[(mt * 16 + lrow) * 32 + q * 8];
            #pragma unroll
            for (int s = 0; s < NS; ++s) {
                bf16x8 bfrag = *(const bf16x8*)&sB[(s * 64 + w * 16 + lrow) * 32 + q * 8];
                if (s < 3) {
                    #pragma unroll
                    for (int mt = 0; mt < 4; ++mt)
                        accS[s][mt] = __builtin_amdgcn_mfma_f32_16x16x32_bf16(af[mt], bfrag, accS[s][mt], 0, 0, 0);
                } else {
                    #pragma unroll
                    for (int mt = 0; mt < 4; ++mt)
                        accF[p][mt] = __builtin_amdgcn_mfma_f32_16x16x32_bf16(af[mt], bfrag, accF[p][mt], 0, 0, 0);
                }
            }
            __syncthreads();
        }
    }

    const int d = dchunk * 64 + w * 16 + lrow;
    const float bI = biasv[d];
    const float bO = biasv[256 + d];
    const float bU = biasv[512 + d];
    const float bF = (NS == 4) ? biasv[768 + d] : 0.0f;
    #pragma unroll
    for (int mt = 0; mt < 4; ++mt) {
        #pragma unroll
        for (int rr = 0; rr < 4; ++rr) {
            const int m = bm0 + mt * 16 + q * 4 + rr;
            if (m >= M) continue;
            float iv = sigf(accS[0][mt][rr] + bI);
            float ov = sigf(accS[1][mt][rr] + bO);
            float uv = tanhf(accS[2][mt][rr] + bU);
            float c;
            if (NS == 4) {
                float fx = accF[0][mt][rr];
                float fl = sigf(fx + accF[NP >= 2 ? 1 : 0][mt][rr] + bF);
                float fr = sigf(fx + accF[NP >= 3 ? 2 : 0][mt][rr] + bF);
                c = iv * uv + fl * cprev[(size_t)m * 512 + d]
                            + fr * cprev[(size_t)m * 512 + 256 + d];
            } else {
                c = iv * uv;
            }
            cout[(size_t)m * 256 + d] = c;
            hout[(size_t)m * 256 + d] = __float2bfloat16(ov * tanhf(c));
        }
    }
}

// ---- tail: levels 10..6, U-weights LDS-stationary, 4 grid barriers -------
__global__ __launch_bounds__(256) void tail_levels(
    __hip_bfloat16* __restrict__ hbuf, float* __restrict__ cbuf,
    const __hip_bfloat16* __restrict__ Wpack,
    const float* __restrict__ preZ,
    unsigned* __restrict__ bar)
{
    __shared__ __hip_bfloat16 sB[8 * 16 * 256];   // 64 KB: U mats for this d-tile
    const int bid = blockIdx.x;
    const int t = threadIdx.x;
    const int dt = bid & 15;     // d-tile
    const int g = bid >> 4;      // m-group 0..3
    const int w = t >> 6, lane = t & 63, lrow = lane & 15, q = lane >> 4;

    // Stage U mats 4..11, rows dt*16..+16, once (LDS survives fences).
    for (int rnd = 0; rnd < 16; ++rnd) {
        int C = rnd * 256 + t;
        int q8k = C & 31, r = (C >> 5) & 15, m8 = C >> 9;
        load_lds16(Wpack + (size_t)((4 + m8) * 256 + dt * 16 + r) * 256 + q8k * 8,
                   &sB[(size_t)C * 8]);
    }
    __syncthreads();

    const int d = dt * 16 + lrow;
    unsigned barnum = 0;

    for (int l = 10; l >= 6; --l) {
        const int n = 1 << l;
        const int start = n - 1;
        const int startc = 2 * n - 1;
        const __hip_bfloat16* hp = hbuf + (size_t)startc * 256;
        const float* cp = cbuf + (size_t)startc * 256;
        __hip_bfloat16* ho = hbuf + (size_t)start * 256;
        float* co = cbuf + (size_t)start * 256;
        const int nmt = n >> 4;

        for (int mt = g * 4 + w; mt < nmt; mt += 16) {
            const int m0 = mt * 16;
            bf16x8 af[2][8];
            #pragma unroll
            for (int p = 0; p < 2; ++p)
                #pragma unroll
                for (int kk = 0; kk < 8; ++kk)
                    af[p][kk] = *(const bf16x8*)(hp + (size_t)(m0 + lrow) * 512 + p * 256 + kk * 32 + q * 8);
            float zi[4][4], clr[2][4];
            #pragma unroll
            for (int rr = 0; rr < 4; ++rr) {
                int m = m0 + q * 4 + rr;
                #pragma unroll
                for (int s = 0; s < 4; ++s)
                    zi[s][rr] = preZ[(size_t)(start + m) * 1024 + s * 256 + d];
                clr[0][rr] = cp[(size_t)m * 512 + d];
                clr[1][rr] = cp[(size_t)m * 512 + 256 + d];
            }

            floatx4 accS[3], accF1, accF2;
            #pragma unroll
            for (int s = 0; s < 3; ++s)
                accS[s] = (floatx4){zi[s][0], zi[s][1], zi[s][2], zi[s][3]};
            accF1 = (floatx4){0.f, 0.f, 0.f, 0.f};
            accF2 = (floatx4){0.f, 0.f, 0.f, 0.f};

            #pragma unroll
            for (int p = 0; p < 2; ++p)
                #pragma unroll
                for (int kk = 0; kk < 8; ++kk)
                    #pragma unroll
                    for (int s = 0; s < 4; ++s) {
                        bf16x8 bfr = *(const bf16x8*)&sB[((p * 4 + s) * 16 + lrow) * 256 + kk * 32 + q * 8];
                        if (s < 3)
                            accS[s] = __builtin_amdgcn_mfma_f32_16x16x32_bf16(af[p][kk], bfr, accS[s], 0, 0, 0);
                        else if (p == 0)
                            accF1 = __builtin_amdgcn_mfma_f32_16x16x32_bf16(af[p][kk], bfr, accF1, 0, 0, 0);
                        else
                            accF2 = __builtin_amdgcn_mfma_f32_16x16x32_bf16(af[p][kk], bfr, accF2, 0, 0, 0);
                    }

            #pragma unroll
            for (int rr = 0; rr < 4; ++rr) {
                int m = m0 + q * 4 + rr;
                float iv = sigf(accS[0][rr]);
                float ov = sigf(accS[1][rr]);
                float uv = tanhf(accS[2][rr]);
                float fx = zi[3][rr];
                float fl = sigf(fx + accF1[rr]);
                float fr = sigf(fx + accF2[rr]);
                float c = iv * uv + fl * clr[0][rr] + fr * clr[1][rr];
                co[(size_t)m * 256 + d] = c;
                ho[(size_t)m * 256 + d] = __float2bfloat16(ov * tanhf(c));
            }
        }

        if (l > 6) {
            // Hierarchical barrier: 8 groups x 8 blocks, RELEASE arrivals,
            // RELAXED spin, one ACQUIRE fence on exit.
            __syncthreads();
            ++barnum;
            if (t == 0) {
                unsigned* gcnt = &bar[(bid >> 3) * 32];
                bool done = false;
                unsigned v = __hip_atomic_fetch_add(gcnt, 1, __ATOMIC_RELEASE,
                                                    __HIP_MEMORY_SCOPE_AGENT) + 1;
                if (v == barnum * 8u) {
                    unsigned r = __hip_atomic_fetch_add(&bar[256], 1, __ATOMIC_RELEASE,
                                                        __HIP_MEMORY_SCOPE_AGENT) + 1;
                    if (r == barnum * 8u) {
                        __hip_atomic_store(&bar[288], barnum, __ATOMIC_RELEASE,
                                           __HIP_MEMORY_SCOPE_AGENT);
                        done = true;
                    }
                }
                if (!done)
                    while (__hip_atomic_load(&bar[288], __ATOMIC_RELAXED,
                                             __HIP_MEMORY_SCOPE_AGENT) < barnum)
                        __builtin_amdgcn_s_sleep(1);
            }
            __syncthreads();
            __builtin_amdgcn_fence(__ATOMIC_ACQUIRE, "agent");
        }
    }
}

// ---- final: levels 5..0 on ONE workgroup (16 waves, one CU) --------------
// Register-budgeted: lb(1024,1) -> 128 VGPR cap; af preloaded per-phase (32).
__global__ __launch_bounds__(1024, 1) void final_levels(
    __hip_bfloat16* __restrict__ hbuf, float* __restrict__ cbuf,
    const __hip_bfloat16* __restrict__ Wpack,
    const float* __restrict__ preZ,
    float* __restrict__ out)
{
    const int t = threadIdx.x;
    const int wave = t >> 6;             // 0..15 = d-tile
    const int lane = t & 63, lrow = lane & 15, q = lane >> 4;
    const int d = wave * 16 + lrow;

    for (int l = 5; l >= 0; --l) {
        const int n = 1 << l;
        const int start = n - 1;
        const int startc = 2 * n - 1;
        const __hip_bfloat16* hp = hbuf + (size_t)startc * 256;
        const float* cp = cbuf + (size_t)startc * 256;
        __hip_bfloat16* ho = hbuf + (size_t)start * 256;
        float* co = cbuf + (size_t)start * 256;
        const int nmt = (n + 15) >> 4;

        for (int mt = 0; mt < nmt; ++mt) {
            const int m0 = mt * 16;
            float zi[4][4], clr[2][4];
            #pragma unroll
            for (int rr = 0; rr < 4; ++rr) {
                int m = m0 + q * 4 + rr;
                #pragma unroll
                for (int s = 0; s < 4; ++s)
                    zi[s][rr] = preZ[(size_t)(start + m) * 1024 + s * 256 + d];
                clr[0][rr] = cp[(size_t)m * 512 + d];
                clr[1][rr] = cp[(size_t)m * 512 + 256 + d];
            }

            floatx4 accS[3], accF1, accF2;
            #pragma unroll
            for (int s = 0; s < 3; ++s)
                accS[s] = (floatx4){zi[s][0], zi[s][1], zi[s][2], zi[s][3]};
            accF1 = (floatx4){0.f, 0.f, 0.f, 0.f};
            accF2 = (floatx4){0.f, 0.f, 0.f, 0.f};

            for (int p = 0; p < 2; ++p) {        // NOT unrolled: caps af live-range
                bf16x8 af[8];
                #pragma unroll
                for (int kk = 0; kk < 8; ++kk)
                    af[kk] = *(const bf16x8*)(hp + (size_t)(m0 + lrow) * 512 + p * 256 + kk * 32 + q * 8);
                #pragma unroll
                for (int kk = 0; kk < 8; ++kk) {
                    #pragma unroll
                    for (int s = 0; s < 3; ++s) {
                        bf16x8 bfr = *(const bf16x8*)(Wpack +
                            (size_t)((4 + p * 4 + s) * 256 + wave * 16 + lrow) * 256 + kk * 32 + q * 8);
                        accS[s] = __builtin_amdgcn_mfma_f32_16x16x32_bf16(af[kk], bfr, accS[s], 0, 0, 0);
                    }
                    bf16x8 bfr = *(const bf16x8*)(Wpack +
                        (size_t)((4 + p * 4 + 3) * 256 + wave * 16 + lrow) * 256 + kk * 32 + q * 8);
                    if (p == 0)
                        accF1 = __builtin_amdgcn_mfma_f32_16x16x32_bf16(af[kk], bfr, accF1, 0, 0, 0);
                    else
                        accF2 = __builtin_amdgcn_mfma_f32_16x16x32_bf16(af[kk], bfr, accF2, 0, 0, 0);
                }
            }

            #pragma unroll
            for (int rr = 0; rr < 4; ++rr) {
                int m = m0 + q * 4 + rr;
                if (m >= n) continue;
                float iv = sigf(accS[0][rr]);
                float ov = sigf(accS[1][rr]);
                float uv = tanhf(accS[2][rr]);
                float fx = zi[3][rr];
                float fl = sigf(fx + accF1[rr]);
                float fr = sigf(fx + accF2[rr]);
                float c = iv * uv + fl * clr[0][rr] + fr * clr[1][rr];
                float hv = ov * tanhf(c);
                if (l == 0) {
                    out[d] = hv;
                    out[256 + d] = c;
                } else {
                    co[(size_t)m * 256 + d] = c;
                    ho[(size_t)m * 256 + d] = __float2bfloat16(hv);
                }
            }
        }
        __syncthreads();
    }
}

extern "C" void kernel_launch(void* const* d_in, const int* in_sizes, int n_in,
                              void* d_out, int out_size, void* d_ws, size_t ws_size,
                              hipStream_t stream)
{
    const float* emb = (const float*)d_in[0];
    const float* Wi  = (const float*)d_in[1];
    const float* bi  = (const float*)d_in[2];
    const float* Ui  = (const float*)d_in[3];
    const float* Wo  = (const float*)d_in[4];
    const float* bo  = (const float*)d_in[5];
    const float* Uo  = (const float*)d_in[6];
    const float* Wu  = (const float*)d_in[7];
    const float* bu  = (const float*)d_in[8];
    const float* Uu  = (const float*)d_in[9];
    const float* Wf  = (const float*)d_in[10];
    const float* bf  = (const float*)d_in[11];
    const float* Uf  = (const float*)d_in[12];

    char* p = (char*)d_ws;
    __hip_bfloat16* Wpack = (__hip_bfloat16*)p;  p += (size_t)12 * 256 * 256 * 2;
    float* biasv          = (float*)p;           p += (size_t)4 * 256 * 4;
    __hip_bfloat16* embB  = (__hip_bfloat16*)p;  p += (size_t)65535 * 256 * 2;
    __hip_bfloat16* hbuf  = (__hip_bfloat16*)p;  p += (size_t)65535 * 256 * 2;
    float* cbuf           = (float*)p;           p += (size_t)65535 * 256 * 4;
    float* preZ           = (float*)p;           p += (size_t)2047 * 1024 * 4;
    unsigned* bar         = (unsigned*)p;        p += 2048;

    pack_weights<<<dim3(12, 256), 256, 0, stream>>>(Wi, bi, Ui, Wo, bo, Uo, Wu, bu, Uu, Wf, bf, Uf,
                                                    Wpack, biasv);
    convert_f32_bf16<<<(65535 * 256 / 4 + 255) / 256, 256, 0, stream>>>(emb, embB, 65535 * 256 / 4);

    // x-phase pre-GEMM for tail nodes (levels 10..0 = nodes 0..2046).
    gemm_zx<<<dim3(16, 32), 256, 0, stream>>>(embB, Wpack, biasv, preZ, 2047);

    // Leaves: level 15, n = 32768. 1 phase, 3 slots, c = i*u.
    {
        const int n = 32768, start = n - 1;
        fused_level<3, 1><<<dim3(4, n / 64), 256, 0, stream>>>(
            embB + (size_t)start * 256, nullptr, nullptr, Wpack, biasv,
            hbuf + (size_t)start * 256, cbuf + (size_t)start * 256, n);
    }
    // Big internal levels 14..11.
    for (int l = 14; l >= 11; --l) {
        const int n = 1 << l;
        const int start = n - 1;
        const int startc = 2 * n - 1;
        fused_level<4, 3><<<dim3(4, n / 64), 256, 0, stream>>>(
            embB + (size_t)start * 256,
            hbuf + (size_t)startc * 256,
            cbuf + (size_t)startc * 256,
            Wpack, biasv,
            hbuf + (size_t)start * 256, cbuf + (size_t)start * 256, n);
    }

    // Tail: levels 10..6 (4 grid barriers), then levels 5..0 on one CU.
    hipMemsetAsync(bar, 0, 2048, stream);
    tail_levels<<<TB, 256, 0, stream>>>(hbuf, cbuf, Wpack, preZ, bar);
    final_levels<<<1, 1024, 0, stream>>>(hbuf, cbuf, Wpack, preZ, (float*)d_out);
}

// Round 10
// 605.317 us; speedup vs baseline: 1.5389x; 1.5389x over previous
//
#include <hip/hip_runtime.h>
#include <hip/hip_bf16.h>
#include <cstdint>
#include <cstddef>

// NaryTreeLSTM bottom-up:
//  - gemm_zx: preZ[node][4*256] = x @ [Wi|Wo|Wu|Wf]^T + bias for nodes 0..2046
//  - levels 15..11: wstat_level — weight-stationary blocks (d-tile 16, U-mats
//    in LDS staged ONCE, bank-rotated layout; A-frags global->VGPR; no K-loop
//    barriers). Leaf variant stages W-mats (3) instead.
//  - levels 10..0: ONE 64-block kernel (R7-proven): U-weights LDS-stationary,
//    hierarchical grid barrier between levels, writes root h,c to out.
//
// Wpack[12][256][256] bf16: mats {Wi,Wo,Wu,Wf, Ui0,Uo0,Uu0,Uf0, Ui1,Uo1,Uu1,Uf1}
// biasv[4][256] fp32. h stored bf16, c fp32.
// f gates: f_l = sig(Wf x + bF + Uf0 h_l), f_r = sig(Wf x + bF + Uf1 h_r).

typedef __attribute__((ext_vector_type(8))) __bf16 bf16x8;
typedef __attribute__((ext_vector_type(4))) float floatx4;

#define TB 64   // tail grid: 16 d-tiles x 4 m-groups

__device__ __forceinline__ float sigf(float x) { return 1.0f / (1.0f + __expf(-x)); }

__device__ __forceinline__ void load_lds16(const void* g, void* l) {
    __builtin_amdgcn_global_load_lds(
        (const __attribute__((address_space(1))) unsigned int*)g,
        (__attribute__((address_space(3))) unsigned int*)l, 16, 0, 0);
}

__global__ void pack_weights(const float* __restrict__ Wi, const float* __restrict__ bi, const float* __restrict__ Ui,
                             const float* __restrict__ Wo, const float* __restrict__ bo, const float* __restrict__ Uo,
                             const float* __restrict__ Wu, const float* __restrict__ bu, const float* __restrict__ Uu,
                             const float* __restrict__ Wf, const float* __restrict__ bf, const float* __restrict__ Uf,
                             __hip_bfloat16* __restrict__ Wpack, float* __restrict__ biasv)
{
    int m = blockIdx.x;   // 0..11
    int d = blockIdx.y;   // 0..255
    int k = threadIdx.x;  // 0..255
    const float* tbl[12] = {Wi, Wo, Wu, Wf,
                            Ui, Uo, Uu, Uf,
                            Ui + 65536, Uo + 65536, Uu + 65536, Uf + 65536};
    Wpack[((size_t)m * 256 + d) * 256 + k] = __float2bfloat16(tbl[m][d * 256 + k]);
    if (m < 4 && k == 0) {
        const float* bt[4] = {bi, bo, bu, bf};
        biasv[m * 256 + d] = bt[m][d];
    }
}

__global__ void convert_f32_bf16(const float* __restrict__ in, __hip_bfloat16* __restrict__ out, int n4)
{
    int i = blockIdx.x * 256 + threadIdx.x;
    if (i >= n4) return;
    float4 v = ((const float4*)in)[i];
    __hip_bfloat16 tmp[4];
    tmp[0] = __float2bfloat16(v.x);
    tmp[1] = __float2bfloat16(v.y);
    tmp[2] = __float2bfloat16(v.z);
    tmp[3] = __float2bfloat16(v.w);
    *(ushort4*)(out + (size_t)i * 4) = *(const ushort4*)tmp;
}

// preZ[m][s*256+d] = sum_k embB[m][k]*Wpack[s*256+d][k] + biasv[s*256+d], m<M
__global__ __launch_bounds__(256) void gemm_zx(
    const __hip_bfloat16* __restrict__ embB,
    const __hip_bfloat16* __restrict__ Wpack,
    const float* __restrict__ biasv,
    float* __restrict__ preZ,
    int M)
{
    __shared__ __hip_bfloat16 sA[64 * 32];
    __shared__ __hip_bfloat16 sB[64 * 32];
    const int t = threadIdx.x;
    const int s = blockIdx.x >> 2;
    const int d0 = (blockIdx.x & 3) * 64;
    const int bm0 = blockIdx.y * 64;
    const int lane = t & 63, w = t >> 6, lrow = lane & 15, q = lane >> 4;

    floatx4 acc[4];
    #pragma unroll
    for (int mt = 0; mt < 4; ++mt) acc[mt] = (floatx4){0.f, 0.f, 0.f, 0.f};

    for (int kk = 0; kk < 8; ++kk) {
        const int k0 = kk * 32;
        {
            int r = t >> 2, kc = t & 3;
            load_lds16(embB + (size_t)(bm0 + r) * 256 + k0 + kc * 8, &sA[t * 8]);
            load_lds16(Wpack + (size_t)(s * 256 + d0 + r) * 256 + k0 + kc * 8, &sB[t * 8]);
        }
        __syncthreads();
        bf16x8 af[4];
        #pragma unroll
        for (int mt = 0; mt < 4; ++mt)
            af[mt] = *(const bf16x8*)&sA[(mt * 16 + lrow) * 32 + q * 8];
        bf16x8 bfr = *(const bf16x8*)&sB[(w * 16 + lrow) * 32 + q * 8];
        #pragma unroll
        for (int mt = 0; mt < 4; ++mt)
            acc[mt] = __builtin_amdgcn_mfma_f32_16x16x32_bf16(af[mt], bfr, acc[mt], 0, 0, 0);
        __syncthreads();
    }

    const int d = d0 + w * 16 + lrow;
    const float bv = biasv[s * 256 + d];
    #pragma unroll
    for (int mt = 0; mt < 4; ++mt)
        #pragma unroll
        for (int rr = 0; rr < 4; ++rr) {
            int m = bm0 + mt * 16 + q * 4 + rr;
            if (m < M) preZ[(size_t)m * 1024 + s * 256 + d] = acc[mt][rr] + bv;
        }
}

// ---- big levels: weight-stationary, no K-loop barriers --------------------
// Block: d-tile = bid&15, m-group g = bid>>4 (G groups). LDS holds the block's
// d-slice of U-mats (internal, 64KB) or W-mats (leaf, 24KB), column-chunks
// rotated by 4*(row&7) so ds_read_b128 hits all 32 banks (<=2 lanes/bank).
// Wave w handles supertiles of 64 rows: st = g*4+w + j*G*4.
template<bool LEAF>
__global__ __launch_bounds__(256, 1) void wstat_level(
    const __hip_bfloat16* __restrict__ embX,   // [.][256]
    const __hip_bfloat16* __restrict__ hprev,  // [.][512]
    const float* __restrict__ cprev,           // [.][512]
    const __hip_bfloat16* __restrict__ Wpack,
    const float* __restrict__ biasv,
    __hip_bfloat16* __restrict__ hout,
    float* __restrict__ cout,
    int n, int G)
{
    constexpr int NMAT = LEAF ? 3 : 8;
    __shared__ __hip_bfloat16 sU[NMAT * 16 * 256];
    const int t = threadIdx.x;
    const int dt = blockIdx.x & 15;
    const int g  = blockIdx.x >> 4;
    const int w = t >> 6, lane = t & 63, lrow = lane & 15, q = lane >> 4;

    // Stage once, swizzled: LDS (mat,row,slot) holds global chunk (slot-4*(row&7))&31.
    #pragma unroll
    for (int it = 0; it < NMAT * 2; ++it) {
        int cid = it * 256 + t;
        int mat = cid >> 9;
        int row = (cid >> 5) & 15;
        int sl  = cid & 31;
        int cc  = (sl - 4 * (row & 7)) & 31;
        load_lds16(Wpack + (size_t)(((LEAF ? 0 : 4) + mat) * 256 + dt * 16 + row) * 256 + cc * 8,
                   &sU[cid * 8]);
    }
    __syncthreads();

    const int rot = q + 4 * (lrow & 7);
    const int d = dt * 16 + lrow;
    const float bI = biasv[d], bO = biasv[256 + d], bU = biasv[512 + d];
    const float bF = LEAF ? 0.0f : biasv[768 + d];

    const int stmax = n >> 6;
    for (int st = g * 4 + w; st < stmax; st += G * 4) {
        const int m0 = st * 64;
        floatx4 accS[3][4];
        floatx4 accF[3][4];
        #pragma unroll
        for (int s = 0; s < 3; ++s)
            #pragma unroll
            for (int mt = 0; mt < 4; ++mt) {
                accS[s][mt] = (floatx4){0.f, 0.f, 0.f, 0.f};
                accF[s][mt] = (floatx4){0.f, 0.f, 0.f, 0.f};
            }

        #pragma unroll
        for (int p = 0; p < (LEAF ? 1 : 3); ++p) {
            const __hip_bfloat16* Ab = (p == 0) ? embX : hprev;
            const int astr = (p == 0) ? 256 : 512;
            const int aoff = (p == 0) ? 0 : (p - 1) * 256;
            #pragma unroll
            for (int kk = 0; kk < 8; ++kk) {
                bf16x8 af[4];
                #pragma unroll
                for (int mt = 0; mt < 4; ++mt)
                    af[mt] = *(const bf16x8*)(Ab + (size_t)(m0 + mt * 16 + lrow) * astr + aoff + kk * 32 + q * 8);
                #pragma unroll
                for (int s = 0; s < (LEAF ? 3 : 4); ++s) {
                    bf16x8 bfr;
                    if (LEAF) {
                        int sl = (kk * 4 + rot) & 31;
                        bfr = *(const bf16x8*)&sU[(s * 16 + lrow) * 256 + sl * 8];
                    } else if (p == 0) {
                        // W-mats (4) read from global: 32KB slice, L1/L2-resident
                        bfr = *(const bf16x8*)(Wpack + (size_t)(s * 256 + dt * 16 + lrow) * 256 + kk * 32 + q * 8);
                    } else {
                        int sl = (kk * 4 + rot) & 31;
                        bfr = *(const bf16x8*)&sU[(((p - 1) * 4 + s) * 16 + lrow) * 256 + sl * 8];
                    }
                    if (s < 3) {
                        #pragma unroll
                        for (int mt = 0; mt < 4; ++mt)
                            accS[s][mt] = __builtin_amdgcn_mfma_f32_16x16x32_bf16(af[mt], bfr, accS[s][mt], 0, 0, 0);
                    } else {
                        #pragma unroll
                        for (int mt = 0; mt < 4; ++mt)
                            accF[p][mt] = __builtin_amdgcn_mfma_f32_16x16x32_bf16(af[mt], bfr, accF[p][mt], 0, 0, 0);
                    }
                }
            }
        }

        #pragma unroll
        for (int mt = 0; mt < 4; ++mt) {
            #pragma unroll
            for (int rr = 0; rr < 4; ++rr) {
                const int m = m0 + mt * 16 + q * 4 + rr;
                float iv = sigf(accS[0][mt][rr] + bI);
                float ov = sigf(accS[1][mt][rr] + bO);
                float uv = tanhf(accS[2][mt][rr] + bU);
                float c;
                if (LEAF) {
                    c = iv * uv;
                } else {
                    float fx = accF[0][mt][rr];
                    float fl = sigf(fx + accF[1][mt][rr] + bF);
                    float fr = sigf(fx + accF[2][mt][rr] + bF);
                    c = iv * uv + fl * cprev[(size_t)m * 512 + d]
                                + fr * cprev[(size_t)m * 512 + 256 + d];
                }
                cout[(size_t)m * 256 + d] = c;
                hout[(size_t)m * 256 + d] = __float2bfloat16(ov * tanhf(c));
            }
        }
    }
}

// ---- tail: levels 10..0, U-weights LDS-stationary, hierarchical barriers --
__global__ __launch_bounds__(256) void tail_levels(
    __hip_bfloat16* __restrict__ hbuf, float* __restrict__ cbuf,
    const __hip_bfloat16* __restrict__ Wpack,
    const float* __restrict__ preZ,
    unsigned* __restrict__ bar, float* __restrict__ out)
{
    __shared__ __hip_bfloat16 sB[8 * 16 * 256];   // 64 KB: U mats for this d-tile
    const int bid = blockIdx.x;
    const int t = threadIdx.x;
    const int dt = bid & 15;     // d-tile
    const int g = bid >> 4;      // m-group 0..3
    const int w = t >> 6, lane = t & 63, lrow = lane & 15, q = lane >> 4;

    for (int rnd = 0; rnd < 16; ++rnd) {
        int C = rnd * 256 + t;
        int q8k = C & 31, r = (C >> 5) & 15, m8 = C >> 9;
        load_lds16(Wpack + (size_t)((4 + m8) * 256 + dt * 16 + r) * 256 + q8k * 8,
                   &sB[(size_t)C * 8]);
    }
    __syncthreads();

    const int d = dt * 16 + lrow;
    unsigned barnum = 0;

    for (int l = 10; l >= 0; --l) {
        const int n = 1 << l;
        const int start = n - 1;
        const int startc = 2 * n - 1;
        const __hip_bfloat16* hp = hbuf + (size_t)startc * 256;
        const float* cp = cbuf + (size_t)startc * 256;
        __hip_bfloat16* ho = hbuf + (size_t)start * 256;
        float* co = cbuf + (size_t)start * 256;
        const int nmt = (n + 15) >> 4;

        for (int mt = g * 4 + w; mt < nmt; mt += 16) {
            const int m0 = mt * 16;
            bf16x8 af[2][8];
            #pragma unroll
            for (int p = 0; p < 2; ++p)
                #pragma unroll
                for (int kk = 0; kk < 8; ++kk)
                    af[p][kk] = *(const bf16x8*)(hp + (size_t)(m0 + lrow) * 512 + p * 256 + kk * 32 + q * 8);
            float zi[4][4], clr[2][4];
            #pragma unroll
            for (int rr = 0; rr < 4; ++rr) {
                int m = m0 + q * 4 + rr;
                #pragma unroll
                for (int s = 0; s < 4; ++s)
                    zi[s][rr] = preZ[(size_t)(start + m) * 1024 + s * 256 + d];
                clr[0][rr] = cp[(size_t)m * 512 + d];
                clr[1][rr] = cp[(size_t)m * 512 + 256 + d];
            }

            floatx4 accS[3], accF1, accF2;
            #pragma unroll
            for (int s = 0; s < 3; ++s)
                accS[s] = (floatx4){zi[s][0], zi[s][1], zi[s][2], zi[s][3]};
            accF1 = (floatx4){0.f, 0.f, 0.f, 0.f};
            accF2 = (floatx4){0.f, 0.f, 0.f, 0.f};

            #pragma unroll
            for (int p = 0; p < 2; ++p)
                #pragma unroll
                for (int kk = 0; kk < 8; ++kk)
                    #pragma unroll
                    for (int s = 0; s < 4; ++s) {
                        bf16x8 bfr = *(const bf16x8*)&sB[((p * 4 + s) * 16 + lrow) * 256 + kk * 32 + q * 8];
                        if (s < 3)
                            accS[s] = __builtin_amdgcn_mfma_f32_16x16x32_bf16(af[p][kk], bfr, accS[s], 0, 0, 0);
                        else if (p == 0)
                            accF1 = __builtin_amdgcn_mfma_f32_16x16x32_bf16(af[p][kk], bfr, accF1, 0, 0, 0);
                        else
                            accF2 = __builtin_amdgcn_mfma_f32_16x16x32_bf16(af[p][kk], bfr, accF2, 0, 0, 0);
                    }

            #pragma unroll
            for (int rr = 0; rr < 4; ++rr) {
                int m = m0 + q * 4 + rr;
                if (m >= n) continue;
                float iv = sigf(accS[0][rr]);
                float ov = sigf(accS[1][rr]);
                float uv = tanhf(accS[2][rr]);
                float fx = zi[3][rr];
                float fl = sigf(fx + accF1[rr]);
                float fr = sigf(fx + accF2[rr]);
                float c = iv * uv + fl * clr[0][rr] + fr * clr[1][rr];
                float hv = ov * tanhf(c);
                if (l == 0) {
                    if (m == 0) { out[d] = hv; out[256 + d] = c; }
                } else {
                    co[(size_t)m * 256 + d] = c;
                    ho[(size_t)m * 256 + d] = __float2bfloat16(hv);
                }
            }
        }

        if (l > 0) {
            // Hierarchical barrier: 8 groups x 8 blocks, RELEASE arrivals,
            // RELAXED spin, one ACQUIRE fence on exit (R6/R7-proven).
            __syncthreads();
            ++barnum;
            if (t == 0) {
                unsigned* gcnt = &bar[(bid >> 3) * 32];
                bool done = false;
                unsigned v = __hip_atomic_fetch_add(gcnt, 1, __ATOMIC_RELEASE,
                                                    __HIP_MEMORY_SCOPE_AGENT) + 1;
                if (v == barnum * 8u) {
                    unsigned r = __hip_atomic_fetch_add(&bar[256], 1, __ATOMIC_RELEASE,
                                                        __HIP_MEMORY_SCOPE_AGENT) + 1;
                    if (r == barnum * 8u) {
                        __hip_atomic_store(&bar[288], barnum, __ATOMIC_RELEASE,
                                           __HIP_MEMORY_SCOPE_AGENT);
                        done = true;
                    }
                }
                if (!done)
                    while (__hip_atomic_load(&bar[288], __ATOMIC_RELAXED,
                                             __HIP_MEMORY_SCOPE_AGENT) < barnum)
                        __builtin_amdgcn_s_sleep(1);
            }
            __syncthreads();
            __builtin_amdgcn_fence(__ATOMIC_ACQUIRE, "agent");
        }
    }
}

extern "C" void kernel_launch(void* const* d_in, const int* in_sizes, int n_in,
                              void* d_out, int out_size, void* d_ws, size_t ws_size,
                              hipStream_t stream)
{
    const float* emb = (const float*)d_in[0];
    const float* Wi  = (const float*)d_in[1];
    const float* bi  = (const float*)d_in[2];
    const float* Ui  = (const float*)d_in[3];
    const float* Wo  = (const float*)d_in[4];
    const float* bo  = (const float*)d_in[5];
    const float* Uo  = (const float*)d_in[6];
    const float* Wu  = (const float*)d_in[7];
    const float* bu  = (const float*)d_in[8];
    const float* Uu  = (const float*)d_in[9];
    const float* Wf  = (const float*)d_in[10];
    const float* bf  = (const float*)d_in[11];
    const float* Uf  = (const float*)d_in[12];

    char* p = (char*)d_ws;
    __hip_bfloat16* Wpack = (__hip_bfloat16*)p;  p += (size_t)12 * 256 * 256 * 2;
    float* biasv          = (float*)p;           p += (size_t)4 * 256 * 4;
    __hip_bfloat16* embB  = (__hip_bfloat16*)p;  p += (size_t)65535 * 256 * 2;
    __hip_bfloat16* hbuf  = (__hip_bfloat16*)p;  p += (size_t)65535 * 256 * 2;
    float* cbuf           = (float*)p;           p += (size_t)65535 * 256 * 4;
    float* preZ           = (float*)p;           p += (size_t)2047 * 1024 * 4;
    unsigned* bar         = (unsigned*)p;        p += 2048;

    pack_weights<<<dim3(12, 256), 256, 0, stream>>>(Wi, bi, Ui, Wo, bo, Uo, Wu, bu, Uu, Wf, bf, Uf,
                                                    Wpack, biasv);
    convert_f32_bf16<<<(65535 * 256 / 4 + 255) / 256, 256, 0, stream>>>(emb, embB, 65535 * 256 / 4);

    // x-phase pre-GEMM for tail nodes (levels 10..0 = nodes 0..2046).
    gemm_zx<<<dim3(16, 32), 256, 0, stream>>>(embB, Wpack, biasv, preZ, 2047);

    // Leaves: level 15, n = 32768. Weight-stationary, W-mats in LDS, G=64.
    {
        const int n = 32768, start = n - 1;
        wstat_level<true><<<16 * 64, 256, 0, stream>>>(
            embB + (size_t)start * 256, nullptr, nullptr, Wpack, biasv,
            hbuf + (size_t)start * 256, cbuf + (size_t)start * 256, n, 64);
    }
    // Big internal levels 14..11. U-mats in LDS (64KB), W from L1/L2, G=32.
    for (int l = 14; l >= 11; --l) {
        const int n = 1 << l;
        const int start = n - 1;
        const int startc = 2 * n - 1;
        wstat_level<false><<<16 * 32, 256, 0, stream>>>(
            embB + (size_t)start * 256,
            hbuf + (size_t)startc * 256,
            cbuf + (size_t)startc * 256,
            Wpack, biasv,
            hbuf + (size_t)start * 256, cbuf + (size_t)start * 256, n, 32);
    }

    // Tail: levels 10..0 in one kernel; writes root h,c to out directly.
    hipMemsetAsync(bar, 0, 2048, stream);
    tail_levels<<<TB, 256, 0, stream>>>(hbuf, cbuf, Wpack, preZ, bar, (float*)d_out);
}

// Round 11
// 443.200 us; speedup vs baseline: 2.1019x; 1.3658x over previous
//
#include <hip/hip_runtime.h>
#include <hip/hip_bf16.h>
#include <cstdint>
#include <cstddef>

// NaryTreeLSTM bottom-up:
//  - gemm_zx: preZ[node][4*256] = x @ [Wi|Wo|Wu|Wf]^T + bias for nodes 0..2046
//  - levels 15..11: fused_level (R4-proven: A staged once/64-row tile, d-chunk 4)
//  - levels 10..0: ONE 64-block kernel; U-weights LDS-stationary; ALL cross-block
//    h/c traffic via relaxed AGENT-scope atomics (sc1 -> LLC, bypasses the
//    non-coherent XCD L2), so the inter-level barrier needs NO acquire fence.
//
// Wpack[12][256][256] bf16: mats {Wi,Wo,Wu,Wf, Ui0,Uo0,Uu0,Uf0, Ui1,Uo1,Uu1,Uf1}
// biasv[4][256] fp32. h stored bf16, c fp32.
// f gates: f_l = sig(Wf x + bF + Uf0 h_l), f_r = sig(Wf x + bF + Uf1 h_r).

typedef __attribute__((ext_vector_type(8))) __bf16 bf16x8;
typedef __attribute__((ext_vector_type(4))) float floatx4;

#define TB 64   // tail grid: 16 d-tiles x 4 m-groups

__device__ __forceinline__ float sigf(float x) { return 1.0f / (1.0f + __expf(-x)); }

__device__ __forceinline__ void load_lds16(const void* g, void* l) {
    __builtin_amdgcn_global_load_lds(
        (const __attribute__((address_space(1))) unsigned int*)g,
        (__attribute__((address_space(3))) unsigned int*)l, 16, 0, 0);
}

// LLC-coherent (cross-XCD) 16B bf16 load as 2x8B relaxed agent atomics.
__device__ __forceinline__ bf16x8 load_h16_llc(const __hip_bfloat16* p) {
    const unsigned long long* q = (const unsigned long long*)p;
    union { unsigned long long u[2]; bf16x8 v; } u;
    u.u[0] = __hip_atomic_load(&q[0], __ATOMIC_RELAXED, __HIP_MEMORY_SCOPE_AGENT);
    u.u[1] = __hip_atomic_load(&q[1], __ATOMIC_RELAXED, __HIP_MEMORY_SCOPE_AGENT);
    return u.v;
}
__device__ __forceinline__ float load_f_llc(const float* p) {
    return __hip_atomic_load(p, __ATOMIC_RELAXED, __HIP_MEMORY_SCOPE_AGENT);
}
__device__ __forceinline__ void store_f_llc(float* p, float v) {
    __hip_atomic_store(p, v, __ATOMIC_RELAXED, __HIP_MEMORY_SCOPE_AGENT);
}
__device__ __forceinline__ void store_h_llc(__hip_bfloat16* p, float v) {
    __hip_bfloat16 h = __float2bfloat16(v);
    unsigned short u;
    __builtin_memcpy(&u, &h, 2);
    __hip_atomic_store((unsigned short*)p, u, __ATOMIC_RELAXED, __HIP_MEMORY_SCOPE_AGENT);
}

__global__ void pack_weights(const float* __restrict__ Wi, const float* __restrict__ bi, const float* __restrict__ Ui,
                             const float* __restrict__ Wo, const float* __restrict__ bo, const float* __restrict__ Uo,
                             const float* __restrict__ Wu, const float* __restrict__ bu, const float* __restrict__ Uu,
                             const float* __restrict__ Wf, const float* __restrict__ bf, const float* __restrict__ Uf,
                             __hip_bfloat16* __restrict__ Wpack, float* __restrict__ biasv)
{
    int m = blockIdx.x;   // 0..11
    int d = blockIdx.y;   // 0..255
    int k = threadIdx.x;  // 0..255
    const float* tbl[12] = {Wi, Wo, Wu, Wf,
                            Ui, Uo, Uu, Uf,
                            Ui + 65536, Uo + 65536, Uu + 65536, Uf + 65536};
    Wpack[((size_t)m * 256 + d) * 256 + k] = __float2bfloat16(tbl[m][d * 256 + k]);
    if (m < 4 && k == 0) {
        const float* bt[4] = {bi, bo, bu, bf};
        biasv[m * 256 + d] = bt[m][d];
    }
}

__global__ void convert_f32_bf16(const float* __restrict__ in, __hip_bfloat16* __restrict__ out, int n4)
{
    int i = blockIdx.x * 256 + threadIdx.x;
    if (i >= n4) return;
    float4 v = ((const float4*)in)[i];
    __hip_bfloat16 tmp[4];
    tmp[0] = __float2bfloat16(v.x);
    tmp[1] = __float2bfloat16(v.y);
    tmp[2] = __float2bfloat16(v.z);
    tmp[3] = __float2bfloat16(v.w);
    *(ushort4*)(out + (size_t)i * 4) = *(const ushort4*)tmp;
}

// preZ[m][s*256+d] = sum_k embB[m][k]*Wpack[s*256+d][k] + biasv[s*256+d], m<M
__global__ __launch_bounds__(256) void gemm_zx(
    const __hip_bfloat16* __restrict__ embB,
    const __hip_bfloat16* __restrict__ Wpack,
    const float* __restrict__ biasv,
    float* __restrict__ preZ,
    int M)
{
    __shared__ __hip_bfloat16 sA[64 * 32];
    __shared__ __hip_bfloat16 sB[64 * 32];
    const int t = threadIdx.x;
    const int s = blockIdx.x >> 2;
    const int d0 = (blockIdx.x & 3) * 64;
    const int bm0 = blockIdx.y * 64;
    const int lane = t & 63, w = t >> 6, lrow = lane & 15, q = lane >> 4;

    floatx4 acc[4];
    #pragma unroll
    for (int mt = 0; mt < 4; ++mt) acc[mt] = (floatx4){0.f, 0.f, 0.f, 0.f};

    for (int kk = 0; kk < 8; ++kk) {
        const int k0 = kk * 32;
        {
            int r = t >> 2, kc = t & 3;
            load_lds16(embB + (size_t)(bm0 + r) * 256 + k0 + kc * 8, &sA[t * 8]);
            load_lds16(Wpack + (size_t)(s * 256 + d0 + r) * 256 + k0 + kc * 8, &sB[t * 8]);
        }
        __syncthreads();
        bf16x8 af[4];
        #pragma unroll
        for (int mt = 0; mt < 4; ++mt)
            af[mt] = *(const bf16x8*)&sA[(mt * 16 + lrow) * 32 + q * 8];
        bf16x8 bfr = *(const bf16x8*)&sB[(w * 16 + lrow) * 32 + q * 8];
        #pragma unroll
        for (int mt = 0; mt < 4; ++mt)
            acc[mt] = __builtin_amdgcn_mfma_f32_16x16x32_bf16(af[mt], bfr, acc[mt], 0, 0, 0);
        __syncthreads();
    }

    const int d = d0 + w * 16 + lrow;
    const float bv = biasv[s * 256 + d];
    #pragma unroll
    for (int mt = 0; mt < 4; ++mt)
        #pragma unroll
        for (int rr = 0; rr < 4; ++rr) {
            int m = bm0 + mt * 16 + q * 4 + rr;
            if (m < M) preZ[(size_t)m * 1024 + s * 256 + d] = acc[mt][rr] + bv;
        }
}

// ---- big levels: fused LDS-tiled kernel (R4-proven) -----------------------
template<int NS, int NP>
__global__ __launch_bounds__(256) void fused_level(
    const __hip_bfloat16* __restrict__ embX,
    const __hip_bfloat16* __restrict__ hprev,
    const float* __restrict__ cprev,
    const __hip_bfloat16* __restrict__ Wpack,
    const float* __restrict__ biasv,
    __hip_bfloat16* __restrict__ hout,
    float* __restrict__ cout,
    int M)
{
    __shared__ __hip_bfloat16 sA[64 * 32];
    __shared__ __hip_bfloat16 sB[NS * 64 * 32];
    const int t = threadIdx.x;
    const int dchunk = blockIdx.x;
    const int bm0 = blockIdx.y * 64;
    const int lane = t & 63;
    const int w = t >> 6;
    const int lrow = lane & 15;
    const int q = lane >> 4;

    floatx4 accS[3][4];
    floatx4 accF[NP][4];
    #pragma unroll
    for (int s = 0; s < 3; ++s)
        #pragma unroll
        for (int mt = 0; mt < 4; ++mt) accS[s][mt] = (floatx4){0.f, 0.f, 0.f, 0.f};
    #pragma unroll
    for (int p = 0; p < NP; ++p)
        #pragma unroll
        for (int mt = 0; mt < 4; ++mt) accF[p][mt] = (floatx4){0.f, 0.f, 0.f, 0.f};

    #pragma unroll
    for (int p = 0; p < NP; ++p) {
        const __hip_bfloat16* Abase = (p == 0) ? embX : hprev;
        const int astride = (p == 0) ? 256 : 512;
        const int aoff = (p == 0) ? 0 : (p - 1) * 256;
        for (int kk = 0; kk < 8; ++kk) {
            const int k0 = kk * 32;
            {
                int r = t >> 2, kc = t & 3;
                load_lds16(Abase + (size_t)(bm0 + r) * astride + aoff + k0 + kc * 8,
                           &sA[t * 8]);
            }
            #pragma unroll
            for (int rep = 0; rep < NS; ++rep) {
                int cid = rep * 256 + t;
                int row = cid >> 2, kc = cid & 3;
                int s = row >> 6, r = row & 63;
                load_lds16(Wpack + (size_t)((p * 4 + s) * 256 + dchunk * 64 + r) * 256 + k0 + kc * 8,
                           &sB[cid * 8]);
            }
            __syncthreads();

            bf16x8 af[4];
            #pragma unroll
            for (int mt = 0; mt < 4; ++mt)
                af[mt] = *(const bf16x8*)&sA[(mt * 16 + lrow) * 32 + q * 8];
            #pragma unroll
            for (int s = 0; s < NS; ++s) {
                bf16x8 bfrag = *(const bf16x8*)&sB[(s * 64 + w * 16 + lrow) * 32 + q * 8];
                if (s < 3) {
                    #pragma unroll
                    for (int mt = 0; mt < 4; ++mt)
                        accS[s][mt] = __builtin_amdgcn_mfma_f32_16x16x32_bf16(af[mt], bfrag, accS[s][mt], 0, 0, 0);
                } else {
                    #pragma unroll
                    for (int mt = 0; mt < 4; ++mt)
                        accF[p][mt] = __builtin_amdgcn_mfma_f32_16x16x32_bf16(af[mt], bfrag, accF[p][mt], 0, 0, 0);
                }
            }
            __syncthreads();
        }
    }

    const int d = dchunk * 64 + w * 16 + lrow;
    const float bI = biasv[d];
    const float bO = biasv[256 + d];
    const float bU = biasv[512 + d];
    const float bF = (NS == 4) ? biasv[768 + d] : 0.0f;
    #pragma unroll
    for (int mt = 0; mt < 4; ++mt) {
        #pragma unroll
        for (int rr = 0; rr < 4; ++rr) {
            const int m = bm0 + mt * 16 + q * 4 + rr;
            if (m >= M) continue;
            float iv = sigf(accS[0][mt][rr] + bI);
            float ov = sigf(accS[1][mt][rr] + bO);
            float uv = tanhf(accS[2][mt][rr] + bU);
            float c;
            if (NS == 4) {
                float fx = accF[0][mt][rr];
                float fl = sigf(fx + accF[NP >= 2 ? 1 : 0][mt][rr] + bF);
                float fr = sigf(fx + accF[NP >= 3 ? 2 : 0][mt][rr] + bF);
                c = iv * uv + fl * cprev[(size_t)m * 512 + d]
                            + fr * cprev[(size_t)m * 512 + 256 + d];
            } else {
                c = iv * uv;
            }
            cout[(size_t)m * 256 + d] = c;
            hout[(size_t)m * 256 + d] = __float2bfloat16(ov * tanhf(c));
        }
    }
}

// ---- tail: levels 10..0, LLC-atomic data path, fence-free barrier ---------
__global__ __launch_bounds__(256) void tail_levels(
    __hip_bfloat16* __restrict__ hbuf, float* __restrict__ cbuf,
    const __hip_bfloat16* __restrict__ Wpack,
    const float* __restrict__ preZ,
    unsigned* __restrict__ bar, float* __restrict__ out)
{
    __shared__ __hip_bfloat16 sB[8 * 16 * 256];   // 64 KB: U mats for this d-tile
    const int bid = blockIdx.x;
    const int t = threadIdx.x;
    const int dt = bid & 15;     // d-tile
    const int g = bid >> 4;      // m-group 0..3
    const int w = t >> 6, lane = t & 63, lrow = lane & 15, q = lane >> 4;

    for (int rnd = 0; rnd < 16; ++rnd) {
        int C = rnd * 256 + t;
        int q8k = C & 31, r = (C >> 5) & 15, m8 = C >> 9;
        load_lds16(Wpack + (size_t)((4 + m8) * 256 + dt * 16 + r) * 256 + q8k * 8,
                   &sB[(size_t)C * 8]);
    }
    __syncthreads();

    const int d = dt * 16 + lrow;
    unsigned barnum = 0;

    for (int l = 10; l >= 0; --l) {
        const int n = 1 << l;
        const int start = n - 1;
        const int startc = 2 * n - 1;
        const __hip_bfloat16* hp = hbuf + (size_t)startc * 256;
        const float* cp = cbuf + (size_t)startc * 256;
        __hip_bfloat16* ho = hbuf + (size_t)start * 256;
        float* co = cbuf + (size_t)start * 256;
        const int nmt = (n + 15) >> 4;

        for (int mt = g * 4 + w; mt < nmt; mt += 16) {
            const int m0 = mt * 16;
            // A fragments: children h via LLC-coherent loads (cross-XCD safe).
            bf16x8 af[2][8];
            #pragma unroll
            for (int p = 0; p < 2; ++p)
                #pragma unroll
                for (int kk = 0; kk < 8; ++kk)
                    af[p][kk] = load_h16_llc(hp + (size_t)(m0 + lrow) * 512 + p * 256 + kk * 32 + q * 8);
            float zi[4][4], clr[2][4];
            #pragma unroll
            for (int rr = 0; rr < 4; ++rr) {
                int m = m0 + q * 4 + rr;
                #pragma unroll
                for (int s = 0; s < 4; ++s)
                    zi[s][rr] = preZ[(size_t)(start + m) * 1024 + s * 256 + d];
                clr[0][rr] = load_f_llc(cp + (size_t)m * 512 + d);
                clr[1][rr] = load_f_llc(cp + (size_t)m * 512 + 256 + d);
            }

            floatx4 accS[3], accF1, accF2;
            #pragma unroll
            for (int s = 0; s < 3; ++s)
                accS[s] = (floatx4){zi[s][0], zi[s][1], zi[s][2], zi[s][3]};
            accF1 = (floatx4){0.f, 0.f, 0.f, 0.f};
            accF2 = (floatx4){0.f, 0.f, 0.f, 0.f};

            #pragma unroll
            for (int p = 0; p < 2; ++p)
                #pragma unroll
                for (int kk = 0; kk < 8; ++kk)
                    #pragma unroll
                    for (int s = 0; s < 4; ++s) {
                        bf16x8 bfr = *(const bf16x8*)&sB[((p * 4 + s) * 16 + lrow) * 256 + kk * 32 + q * 8];
                        if (s < 3)
                            accS[s] = __builtin_amdgcn_mfma_f32_16x16x32_bf16(af[p][kk], bfr, accS[s], 0, 0, 0);
                        else if (p == 0)
                            accF1 = __builtin_amdgcn_mfma_f32_16x16x32_bf16(af[p][kk], bfr, accF1, 0, 0, 0);
                        else
                            accF2 = __builtin_amdgcn_mfma_f32_16x16x32_bf16(af[p][kk], bfr, accF2, 0, 0, 0);
                    }

            #pragma unroll
            for (int rr = 0; rr < 4; ++rr) {
                int m = m0 + q * 4 + rr;
                if (m >= n) continue;
                float iv = sigf(accS[0][rr]);
                float ov = sigf(accS[1][rr]);
                float uv = tanhf(accS[2][rr]);
                float fx = zi[3][rr];
                float fl = sigf(fx + accF1[rr]);
                float fr = sigf(fx + accF2[rr]);
                float c = iv * uv + fl * clr[0][rr] + fr * clr[1][rr];
                float hv = ov * tanhf(c);
                if (l == 0) {
                    if (m == 0) { out[d] = hv; out[256 + d] = c; }
                } else {
                    store_f_llc(co + (size_t)m * 256 + d, c);
                    store_h_llc(ho + (size_t)m * 256 + d, hv);
                }
            }
        }

        if (l > 0) {
            // Barrier: RELEASE arrivals (drain stores; L2 has no dirty h/c
            // lines since the data path is sc1), RELAXED spin, NO agent
            // acquire fence (loads are LLC-coherent); workgroup fence only
            // for compile-time ordering.
            __syncthreads();
            ++barnum;
            if (t == 0) {
                unsigned* gcnt = &bar[(bid >> 3) * 32];
                bool done = false;
                unsigned v = __hip_atomic_fetch_add(gcnt, 1, __ATOMIC_RELEASE,
                                                    __HIP_MEMORY_SCOPE_AGENT) + 1;
                if (v == barnum * 8u) {
                    unsigned r = __hip_atomic_fetch_add(&bar[256], 1, __ATOMIC_RELEASE,
                                                        __HIP_MEMORY_SCOPE_AGENT) + 1;
                    if (r == barnum * 8u) {
                        __hip_atomic_store(&bar[288], barnum, __ATOMIC_RELEASE,
                                           __HIP_MEMORY_SCOPE_AGENT);
                        done = true;
                    }
                }
                if (!done)
                    while (__hip_atomic_load(&bar[288], __ATOMIC_RELAXED,
                                             __HIP_MEMORY_SCOPE_AGENT) < barnum)
                        __builtin_amdgcn_s_sleep(1);
            }
            __syncthreads();
            __builtin_amdgcn_fence(__ATOMIC_ACQUIRE, "workgroup");
        }
    }
}

extern "C" void kernel_launch(void* const* d_in, const int* in_sizes, int n_in,
                              void* d_out, int out_size, void* d_ws, size_t ws_size,
                              hipStream_t stream)
{
    const float* emb = (const float*)d_in[0];
    const float* Wi  = (const float*)d_in[1];
    const float* bi  = (const float*)d_in[2];
    const float* Ui  = (const float*)d_in[3];
    const float* Wo  = (const float*)d_in[4];
    const float* bo  = (const float*)d_in[5];
    const float* Uo  = (const float*)d_in[6];
    const float* Wu  = (const float*)d_in[7];
    const float* bu  = (const float*)d_in[8];
    const float* Uu  = (const float*)d_in[9];
    const float* Wf  = (const float*)d_in[10];
    const float* bf  = (const float*)d_in[11];
    const float* Uf  = (const float*)d_in[12];

    char* p = (char*)d_ws;
    __hip_bfloat16* Wpack = (__hip_bfloat16*)p;  p += (size_t)12 * 256 * 256 * 2;
    float* biasv          = (float*)p;           p += (size_t)4 * 256 * 4;
    __hip_bfloat16* embB  = (__hip_bfloat16*)p;  p += (size_t)65535 * 256 * 2;
    __hip_bfloat16* hbuf  = (__hip_bfloat16*)p;  p += (size_t)65535 * 256 * 2;
    float* cbuf           = (float*)p;           p += (size_t)65535 * 256 * 4;
    float* preZ           = (float*)p;           p += (size_t)2047 * 1024 * 4;
    unsigned* bar         = (unsigned*)p;        p += 2048;

    pack_weights<<<dim3(12, 256), 256, 0, stream>>>(Wi, bi, Ui, Wo, bo, Uo, Wu, bu, Uu, Wf, bf, Uf,
                                                    Wpack, biasv);
    convert_f32_bf16<<<(65535 * 256 / 4 + 255) / 256, 256, 0, stream>>>(emb, embB, 65535 * 256 / 4);

    // x-phase pre-GEMM for tail nodes (levels 10..0 = nodes 0..2046).
    gemm_zx<<<dim3(16, 32), 256, 0, stream>>>(embB, Wpack, biasv, preZ, 2047);

    // Leaves: level 15, n = 32768. 1 phase, 3 slots, c = i*u.
    {
        const int n = 32768, start = n - 1;
        fused_level<3, 1><<<dim3(4, n / 64), 256, 0, stream>>>(
            embB + (size_t)start * 256, nullptr, nullptr, Wpack, biasv,
            hbuf + (size_t)start * 256, cbuf + (size_t)start * 256, n);
    }
    // Big internal levels 14..11.
    for (int l = 14; l >= 11; --l) {
        const int n = 1 << l;
        const int start = n - 1;
        const int startc = 2 * n - 1;
        fused_level<4, 3><<<dim3(4, n / 64), 256, 0, stream>>>(
            embB + (size_t)start * 256,
            hbuf + (size_t)startc * 256,
            cbuf + (size_t)startc * 256,
            Wpack, biasv,
            hbuf + (size_t)start * 256, cbuf + (size_t)start * 256, n);
    }

    // Tail: levels 10..0 in one kernel; writes root h,c to out directly.
    hipMemsetAsync(bar, 0, 2048, stream);
    tail_levels<<<TB, 256, 0, stream>>>(hbuf, cbuf, Wpack, preZ, bar, (float*)d_out);
}